// Round 2
// baseline (633.549 us; speedup 1.0000x reference)
//
#include <hip/hip_runtime.h>
#include <hip/hip_bf16.h>

#define N_NODES 100000
#define N_EDGES 1600000

// ---------------- CSR build ----------------

__global__ __launch_bounds__(256) void k_count(const int* __restrict__ dst,
                                               int* __restrict__ cnt, int nE) {
    int e = blockIdx.x * 256 + threadIdx.x;
    if (e < nE) atomicAdd(&cnt[dst[e]], 1);
}

__global__ __launch_bounds__(256) void k_scanA(const int* __restrict__ cnt,
                                               int* __restrict__ rowptr,
                                               int* __restrict__ partials, int n) {
    __shared__ int s[256];
    int t = threadIdx.x;
    int i = blockIdx.x * 256 + t;
    int val = (i < n) ? cnt[i] : 0;
    s[t] = val;
    __syncthreads();
    for (int off = 1; off < 256; off <<= 1) {
        int x = (t >= off) ? s[t - off] : 0;
        __syncthreads();
        if (t >= off) s[t] += x;
        __syncthreads();
    }
    if (i < n) rowptr[i] = s[t] - val;   // exclusive within block
    if (t == 255) partials[blockIdx.x] = s[255];
}

__global__ __launch_bounds__(512) void k_scanB(const int* __restrict__ partials,
                                               int* __restrict__ offsets, int nb) {
    __shared__ int s[512];
    int t = threadIdx.x;
    int val = (t < nb) ? partials[t] : 0;
    s[t] = val;
    __syncthreads();
    for (int off = 1; off < 512; off <<= 1) {
        int x = (t >= off) ? s[t - off] : 0;
        __syncthreads();
        if (t >= off) s[t] += x;
        __syncthreads();
    }
    if (t < nb) offsets[t] = s[t] - val; // exclusive over blocks
}

__global__ __launch_bounds__(256) void k_scanC(int* __restrict__ rowptr,
                                               const int* __restrict__ offsets,
                                               int* __restrict__ cursor, int n, int nE) {
    int i = blockIdx.x * 256 + threadIdx.x;
    if (i < n) {
        int r = rowptr[i] + offsets[i >> 8];
        rowptr[i] = r;
        cursor[i] = r;
    }
    if (i == 0) rowptr[n] = nE;
}

__global__ __launch_bounds__(256) void k_fill(const int* __restrict__ src,
                                              const int* __restrict__ dst,
                                              int* __restrict__ cursor,
                                              int* __restrict__ csr_src, int nE) {
    int e = blockIdx.x * 256 + threadIdx.x;
    if (e < nE) {
        int p = atomicAdd(&cursor[dst[e]], 1);
        csr_src[p] = src[e];
    }
}

// ---- Fused SAGE layer: mean-agg + h@Ws + agg@Wn + b (all fp32) ----
// One wave (64 lanes) per node; lane = feature index.
// RELU_IN: apply ReLU to the input features at load time (input is the
// previous layer's pre-activation, stored in d_out).
// Weights staged in LDS (k*OUT_DIM+lane -> 2 lanes/bank = conflict-free).
// Per-node h/agg rows staged in wave-private LDS (same-wave DS ordering,
// no block barrier needed).

template <int OUT_DIM, bool RELU_IN>
__global__ __launch_bounds__(256) void k_layer(const float* __restrict__ h,
                                               const int* __restrict__ rowptr,
                                               const int* __restrict__ csr,
                                               const float* __restrict__ Ws,
                                               const float* __restrict__ Wn,
                                               const float* __restrict__ bias,
                                               float* __restrict__ out) {
    __shared__ float sWs[64 * OUT_DIM];
    __shared__ float sWn[64 * OUT_DIM];
    __shared__ float sB[OUT_DIM];
    __shared__ float sH[4][64];
    __shared__ float sA[4][64];

    int t = threadIdx.x;
    for (int i = t; i < 64 * OUT_DIM; i += 256) {
        sWs[i] = Ws[i];
        sWn[i] = Wn[i];
    }
    if (t < OUT_DIM) sB[t] = bias[t];
    __syncthreads();

    int w = t >> 6;
    int lane = t & 63;

    for (int v = blockIdx.x * 4 + w; v < N_NODES; v += gridDim.x * 4) {
        int beg = rowptr[v];
        int end = rowptr[v + 1];
        float acc = 0.f;

        // gather: wave-uniform neighbor ids broadcast via shfl; each row load
        // is 64 lanes x 4B = 256B fully coalesced
        for (int e0 = beg; e0 < end; e0 += 64) {
            int n = end - e0;
            if (n > 64) n = 64;
            int s = (lane < n) ? csr[e0 + lane] : 0;
            int i = 0;
            for (; i + 4 <= n; i += 4) {
                int s0 = __shfl(s, i);
                int s1 = __shfl(s, i + 1);
                int s2 = __shfl(s, i + 2);
                int s3 = __shfl(s, i + 3);
                float x0 = h[s0 * 64 + lane];
                float x1 = h[s1 * 64 + lane];
                float x2 = h[s2 * 64 + lane];
                float x3 = h[s3 * 64 + lane];
                if (RELU_IN) {
                    x0 = fmaxf(x0, 0.f); x1 = fmaxf(x1, 0.f);
                    x2 = fmaxf(x2, 0.f); x3 = fmaxf(x3, 0.f);
                }
                acc += x0; acc += x1; acc += x2; acc += x3;
            }
            for (; i < n; ++i) {
                int si = __shfl(s, i);
                float x = h[si * 64 + lane];
                if (RELU_IN) x = fmaxf(x, 0.f);
                acc += x;
            }
        }

        float deg = (float)(end - beg);
        float a = acc / fmaxf(deg, 1.0f);
        float hv = h[v * 64 + lane];
        if (RELU_IN) hv = fmaxf(hv, 0.f);

        sH[w][lane] = hv;
        sA[w][lane] = a;
        // same-wave LDS RAW: compiler inserts lgkmcnt waits; no __syncthreads.

        if (lane < OUT_DIM) {
            float o = sB[lane];
#pragma unroll 8
            for (int k = 0; k < 64; ++k) {
                o += sH[w][k] * sWs[k * OUT_DIM + lane];  // sH broadcast (free)
                o += sA[w][k] * sWn[k * OUT_DIM + lane];  // stride-1 over lanes
            }
            out[v * OUT_DIM + lane] = o;
        }
    }
}

// ---------------- launch ----------------

extern "C" void kernel_launch(void* const* d_in, const int* in_sizes, int n_in,
                              void* d_out, int out_size, void* d_ws, size_t ws_size,
                              hipStream_t stream) {
    const float* feat = (const float*)d_in[0];
    const int* ei = (const int*)d_in[1];
    const int* src = ei;
    const int* dst = ei + N_EDGES;
    const float* Ws0 = (const float*)d_in[2];
    const float* Wn0 = (const float*)d_in[3];
    const float* b0  = (const float*)d_in[4];
    const float* Ws1 = (const float*)d_in[5];
    const float* Wn1 = (const float*)d_in[6];
    const float* b1  = (const float*)d_in[7];
    const float* Ws2 = (const float*)d_in[8];
    const float* Wn2 = (const float*)d_in[9];
    const float* b2  = (const float*)d_in[10];

    float* out = (float*)d_out;
    float* out_h3 = out;                                 // [N,16]
    float* out_e0 = out + (size_t)N_NODES * 16;          // [N,64]  pre-relu h1
    float* out_e1 = out + (size_t)N_NODES * (16 + 64);   // [N,64]  pre-relu h2

    char* ws = (char*)d_ws;
    size_t off = 0;
    auto alloc = [&](size_t bytes) -> void* {
        void* p = ws + off;
        off = (off + bytes + 255) & ~(size_t)255;
        return p;
    };
    int* cnt      = (int*)alloc(N_NODES * sizeof(int));
    int* rowptr   = (int*)alloc((N_NODES + 1) * sizeof(int));
    int* cursor   = (int*)alloc(N_NODES * sizeof(int));
    int* partials = (int*)alloc(512 * sizeof(int));
    int* offsets  = (int*)alloc(512 * sizeof(int));
    int* csr      = (int*)alloc(N_EDGES * sizeof(int));  // total ~8.2 MB
    (void)ws_size;

    hipMemsetAsync(cnt, 0, N_NODES * sizeof(int), stream);

    int ebl = (N_EDGES + 255) / 256;
    int nbl = (N_NODES + 255) / 256;

    k_count<<<ebl, 256, 0, stream>>>(dst, cnt, N_EDGES);
    k_scanA<<<nbl, 256, 0, stream>>>(cnt, rowptr, partials, N_NODES);
    k_scanB<<<1, 512, 0, stream>>>(partials, offsets, nbl);
    k_scanC<<<nbl, 256, 0, stream>>>(rowptr, offsets, cursor, N_NODES, N_EDGES);
    k_fill<<<ebl, 256, 0, stream>>>(src, dst, cursor, csr, N_EDGES);

    // layer 1: input feat (no relu), out = embed0 (pre-relu h1)
    k_layer<64, false><<<1024, 256, 0, stream>>>(feat, rowptr, csr, Ws0, Wn0, b0, out_e0);
    // layer 2: input relu(embed0), out = embed1 (pre-relu h2)
    k_layer<64, true><<<1024, 256, 0, stream>>>(out_e0, rowptr, csr, Ws1, Wn1, b1, out_e1);
    // layer 3: input relu(embed1), out = h3
    k_layer<16, true><<<1024, 256, 0, stream>>>(out_e1, rowptr, csr, Ws2, Wn2, b2, out_h3);
}

// Round 3
// 483.362 us; speedup vs baseline: 1.3107x; 1.3107x over previous
//
#include <hip/hip_runtime.h>
#include <hip/hip_bf16.h>

typedef __hip_bfloat16 bf16;

#define N_NODES 100000
#define N_EDGES 1600000
#define NBUCK 391           // ceil(N_NODES/256), bucket = dst >> 8
#define PAD 16              // cursor padding: one 64B line per bucket

// ================= CSR build: LDS-aggregated bucket sort =================

// p1: global bucket histogram via per-block LDS histograms
__global__ __launch_bounds__(256) void p1_hist(const int* __restrict__ dst,
                                               int* __restrict__ gcnt_pad, int nE) {
    __shared__ int hist[NBUCK];
    int t = threadIdx.x;
    for (int i = t; i < NBUCK; i += 256) hist[i] = 0;
    __syncthreads();
    for (int e = blockIdx.x * 256 + t; e < nE; e += gridDim.x * 256)
        atomicAdd(&hist[dst[e] >> 8], 1);
    __syncthreads();
    for (int i = t; i < NBUCK; i += 256)
        if (hist[i]) atomicAdd(&gcnt_pad[i * PAD], hist[i]);
}

// p2: exclusive scan of bucket counts (single block); init padded cursors
__global__ __launch_bounds__(512) void p2_scan(const int* __restrict__ gcnt_pad,
                                               int* __restrict__ bucket_base,
                                               int* __restrict__ gcur_pad, int nE) {
    __shared__ int s[512];
    int t = threadIdx.x;
    int val = (t < NBUCK) ? gcnt_pad[t * PAD] : 0;
    s[t] = val;
    __syncthreads();
    for (int off = 1; off < 512; off <<= 1) {
        int x = (t >= off) ? s[t - off] : 0;
        __syncthreads();
        if (t >= off) s[t] += x;
        __syncthreads();
    }
    if (t < NBUCK) {
        int excl = s[t] - val;
        bucket_base[t] = excl;
        gcur_pad[t * PAD] = excl;
    }
    if (t == NBUCK - 1) bucket_base[NBUCK] = nE;
}

// p3: scatter packed (dstlocal<<17 | src) into bucket regions.
// Per-block: LDS histogram -> one global atomic per touched bucket to
// reserve a range -> LDS cursors -> scatter.
__global__ __launch_bounds__(256) void p3_scatter(const int* __restrict__ src,
                                                  const int* __restrict__ dst,
                                                  int* __restrict__ gcur_pad,
                                                  unsigned int* __restrict__ packed, int nE) {
    __shared__ int hist[NBUCK];
    __shared__ int cur[NBUCK];
    int t = threadIdx.x;
    int chunk = (nE + gridDim.x - 1) / gridDim.x;
    int lo = blockIdx.x * chunk;
    int hi = min(nE, lo + chunk);

    for (int i = t; i < NBUCK; i += 256) hist[i] = 0;
    __syncthreads();
    for (int e = lo + t; e < hi; e += 256)
        atomicAdd(&hist[dst[e] >> 8], 1);
    __syncthreads();
    for (int i = t; i < NBUCK; i += 256)
        cur[i] = hist[i] ? atomicAdd(&gcur_pad[i * PAD], hist[i]) : 0;
    __syncthreads();
    for (int e = lo + t; e < hi; e += 256) {
        int d = dst[e];
        int b = d >> 8;
        int pos = atomicAdd(&cur[b], 1);           // absolute position
        packed[pos] = ((unsigned int)(d & 255) << 17) | (unsigned int)src[e];
    }
}

// p4: one block per bucket -> local count/scan/scatter in LDS, write CSR + rowptr
__global__ __launch_bounds__(256) void p4_build(const unsigned int* __restrict__ packed,
                                                const int* __restrict__ bucket_base,
                                                int* __restrict__ rowptr,
                                                int* __restrict__ csr, int nN, int nE) {
    __shared__ int cnt[256];
    __shared__ int s[256];
    __shared__ int curs[256];
    int b = blockIdx.x;
    int t = threadIdx.x;
    int node0 = b << 8;
    int ebase = bucket_base[b];
    int eend  = bucket_base[b + 1];

    cnt[t] = 0;
    __syncthreads();
    for (int e = ebase + t; e < eend; e += 256)
        atomicAdd(&cnt[packed[e] >> 17], 1);
    __syncthreads();
    int val = cnt[t];
    s[t] = val;
    __syncthreads();
    for (int off = 1; off < 256; off <<= 1) {
        int x = (t >= off) ? s[t - off] : 0;
        __syncthreads();
        if (t >= off) s[t] += x;
        __syncthreads();
    }
    int excl = s[t] - val;
    int node = node0 + t;
    if (node < nN) rowptr[node] = ebase + excl;
    curs[t] = ebase + excl;
    if (b == gridDim.x - 1 && t == 0) rowptr[nN] = nE;
    __syncthreads();
    for (int e = ebase + t; e < eend; e += 256) {
        unsigned int p = packed[e];
        int d = p >> 17;
        int pos = atomicAdd(&curs[d], 1);
        csr[pos] = (int)(p & 0x1FFFFu);
    }
}

// ===== Fused SAGE layer (64-out): mean-agg + h@Ws + agg@Wn + b =====
// One wave per node; lane = feature. bf16 weights in LDS (16.4 KB total ->
// 8 blocks/CU), fp32 accumulation. Wave-private sH/sA staging.

template <bool RELU_IN>
__global__ __launch_bounds__(256, 8) void k_layer64(const float* __restrict__ h,
                                                    const int* __restrict__ rowptr,
                                                    const int* __restrict__ csr,
                                                    const float* __restrict__ Ws,
                                                    const float* __restrict__ Wn,
                                                    const float* __restrict__ bias,
                                                    float* __restrict__ out) {
    __shared__ bf16 sWs[64 * 64];
    __shared__ bf16 sWn[64 * 64];
    __shared__ float sB[64];
    __shared__ float sH[4][64];
    __shared__ float sA[4][64];

    int t = threadIdx.x;
    for (int i = t; i < 64 * 64; i += 256) {
        sWs[i] = (bf16)Ws[i];
        sWn[i] = (bf16)Wn[i];
    }
    if (t < 64) sB[t] = bias[t];
    __syncthreads();

    int w = t >> 6;
    int lane = t & 63;

    for (int v = blockIdx.x * 4 + w; v < N_NODES; v += gridDim.x * 4) {
        int beg = rowptr[v];
        int end = rowptr[v + 1];
        float acc = 0.f;

        for (int e0 = beg; e0 < end; e0 += 64) {
            int n = end - e0;
            if (n > 64) n = 64;
            int si = (lane < n) ? csr[e0 + lane] : 0;
            int i = 0;
            for (; i + 4 <= n; i += 4) {
                int s0 = __shfl(si, i);
                int s1 = __shfl(si, i + 1);
                int s2 = __shfl(si, i + 2);
                int s3 = __shfl(si, i + 3);
                float x0 = h[s0 * 64 + lane];
                float x1 = h[s1 * 64 + lane];
                float x2 = h[s2 * 64 + lane];
                float x3 = h[s3 * 64 + lane];
                if (RELU_IN) {
                    x0 = fmaxf(x0, 0.f); x1 = fmaxf(x1, 0.f);
                    x2 = fmaxf(x2, 0.f); x3 = fmaxf(x3, 0.f);
                }
                acc += x0; acc += x1; acc += x2; acc += x3;
            }
            for (; i < n; ++i) {
                int sj = __shfl(si, i);
                float x = h[sj * 64 + lane];
                if (RELU_IN) x = fmaxf(x, 0.f);
                acc += x;
            }
        }

        float deg = (float)(end - beg);
        float a = acc / fmaxf(deg, 1.0f);
        float hv = h[v * 64 + lane];
        if (RELU_IN) hv = fmaxf(hv, 0.f);

        sH[w][lane] = hv;
        sA[w][lane] = a;
        // same-wave LDS RAW; compiler inserts lgkmcnt waits, no barrier needed

        float o = sB[lane];
#pragma unroll 8
        for (int k = 0; k < 64; ++k) {
            o += sH[w][k] * (float)sWs[k * 64 + lane];
            o += sA[w][k] * (float)sWn[k * 64 + lane];
        }
        out[v * 64 + lane] = o;
    }
}

// ===== Layer 3 split: project first (16-wide), then gather small rows =====

// z = relu(h2) @ Wn2, w = relu(h2) @ Ws2 + b2   (both [N,16])
__global__ __launch_bounds__(256) void k_pre3(const float* __restrict__ h,
                                              const float* __restrict__ Ws,
                                              const float* __restrict__ Wn,
                                              const float* __restrict__ bias,
                                              float* __restrict__ zbuf,
                                              float* __restrict__ wbuf) {
    __shared__ float sWs[64 * 16];
    __shared__ float sWn[64 * 16];
    __shared__ float sB[16];
    __shared__ float sH[4][64];

    int t = threadIdx.x;
    for (int i = t; i < 64 * 16; i += 256) {
        sWs[i] = Ws[i];
        sWn[i] = Wn[i];
    }
    if (t < 16) sB[t] = bias[t];
    __syncthreads();

    int w = t >> 6;
    int lane = t & 63;
    int j = lane & 15;
    int sel = lane >> 4;   // 0: wbuf (Ws+b), 1: zbuf (Wn), 2/3: idle in compute

    for (int v = blockIdx.x * 4 + w; v < N_NODES; v += gridDim.x * 4) {
        sH[w][lane] = fmaxf(h[v * 64 + lane], 0.f);
        if (sel < 2) {
            const float* W = sel ? sWn : sWs;
            float o = sel ? 0.f : sB[j];
#pragma unroll 8
            for (int k = 0; k < 64; ++k) o += sH[w][k] * W[k * 16 + j];
            if (sel) zbuf[v * 16 + j] = o;
            else     wbuf[v * 16 + j] = o;
        }
    }
}

// out3 = wbuf + segmean(zbuf[src], dst): 64B row gather, 4 edges/wave-step
__global__ __launch_bounds__(256, 8) void k_gather3(const int* __restrict__ rowptr,
                                                    const int* __restrict__ csr,
                                                    const float* __restrict__ zbuf,
                                                    const float* __restrict__ wbuf,
                                                    float* __restrict__ out) {
    int t = threadIdx.x;
    int w = t >> 6;
    int lane = t & 63;
    int g = lane >> 4;     // edge subgroup 0..3
    int j = lane & 15;     // feature

    for (int v = blockIdx.x * 4 + w; v < N_NODES; v += gridDim.x * 4) {
        int beg = rowptr[v];
        int end = rowptr[v + 1];
        float acc = 0.f;
        int e = beg + g;
        for (; e + 4 < end; e += 8) {
            float a0 = zbuf[csr[e] * 16 + j];
            float a1 = zbuf[csr[e + 4] * 16 + j];
            acc += a0;
            acc += a1;
        }
        if (e < end) acc += zbuf[csr[e] * 16 + j];
        acc += __shfl_xor(acc, 16);
        acc += __shfl_xor(acc, 32);
        if (g == 0) {
            float deg = (float)(end - beg);
            out[v * 16 + j] = wbuf[v * 16 + j] + acc / fmaxf(deg, 1.0f);
        }
    }
}

// ---------------- launch ----------------

extern "C" void kernel_launch(void* const* d_in, const int* in_sizes, int n_in,
                              void* d_out, int out_size, void* d_ws, size_t ws_size,
                              hipStream_t stream) {
    const float* feat = (const float*)d_in[0];
    const int* ei = (const int*)d_in[1];
    const int* src = ei;
    const int* dst = ei + N_EDGES;
    const float* Ws0 = (const float*)d_in[2];
    const float* Wn0 = (const float*)d_in[3];
    const float* b0  = (const float*)d_in[4];
    const float* Ws1 = (const float*)d_in[5];
    const float* Wn1 = (const float*)d_in[6];
    const float* b1  = (const float*)d_in[7];
    const float* Ws2 = (const float*)d_in[8];
    const float* Wn2 = (const float*)d_in[9];
    const float* b2  = (const float*)d_in[10];

    float* out = (float*)d_out;
    float* out_h3 = out;                                 // [N,16]
    float* out_e0 = out + (size_t)N_NODES * 16;          // [N,64]  pre-relu h1
    float* out_e1 = out + (size_t)N_NODES * (16 + 64);   // [N,64]  pre-relu h2

    char* ws = (char*)d_ws;
    size_t off = 0;
    auto alloc = [&](size_t bytes) -> void* {
        void* p = ws + off;
        off = (off + bytes + 255) & ~(size_t)255;
        return p;
    };
    int* gcnt_pad    = (int*)alloc(NBUCK * PAD * sizeof(int));     // 25 KB
    int* gcur_pad    = (int*)alloc(NBUCK * PAD * sizeof(int));
    int* bucket_base = (int*)alloc((NBUCK + 1) * sizeof(int));
    int* rowptr      = (int*)alloc((N_NODES + 1) * sizeof(int));
    unsigned int* packed = (unsigned int*)alloc(N_EDGES * sizeof(int)); // 6.4 MB
    int* csr         = (int*)alloc(N_EDGES * sizeof(int));              // 6.4 MB
    float* zbuf      = (float*)alloc((size_t)N_NODES * 16 * sizeof(float));
    float* wbuf      = (float*)alloc((size_t)N_NODES * 16 * sizeof(float));
    (void)ws_size;

    hipMemsetAsync(gcnt_pad, 0, NBUCK * PAD * sizeof(int), stream);

    p1_hist<<<128, 256, 0, stream>>>(dst, gcnt_pad, N_EDGES);
    p2_scan<<<1, 512, 0, stream>>>(gcnt_pad, bucket_base, gcur_pad, N_EDGES);
    p3_scatter<<<128, 256, 0, stream>>>(src, dst, gcur_pad, packed, N_EDGES);
    p4_build<<<NBUCK, 256, 0, stream>>>(packed, bucket_base, rowptr, csr, N_NODES, N_EDGES);

    // layer 1: input feat (no relu), out = embed0 (pre-relu h1)
    k_layer64<false><<<2048, 256, 0, stream>>>(feat, rowptr, csr, Ws0, Wn0, b0, out_e0);
    // layer 2: input relu(embed0), out = embed1 (pre-relu h2)
    k_layer64<true><<<2048, 256, 0, stream>>>(out_e0, rowptr, csr, Ws1, Wn1, b1, out_e1);
    // layer 3: project relu(embed1) to 16 wide, then gather 64B rows
    k_pre3<<<1024, 256, 0, stream>>>(out_e1, Ws2, Wn2, b2, zbuf, wbuf);
    k_gather3<<<2048, 256, 0, stream>>>(rowptr, csr, zbuf, wbuf, out_h3);
}

// Round 6
// 475.558 us; speedup vs baseline: 1.3322x; 1.0164x over previous
//
#include <hip/hip_runtime.h>
#include <hip/hip_bf16.h>

#define N_NODES 100000
#define N_EDGES 1600000
#define NBUCK 391           // ceil(N_NODES/256), bucket = dst >> 8
#define PAD 16              // cursor padding: one 64B line per bucket

// ================= CSR build: LDS-aggregated bucket sort (proven r3) =================

__global__ __launch_bounds__(256) void p1_hist(const int* __restrict__ dst,
                                               int* __restrict__ gcnt_pad, int nE) {
    __shared__ int hist[NBUCK];
    int t = threadIdx.x;
    for (int i = t; i < NBUCK; i += 256) hist[i] = 0;
    __syncthreads();
    for (int e = blockIdx.x * 256 + t; e < nE; e += gridDim.x * 256)
        atomicAdd(&hist[dst[e] >> 8], 1);
    __syncthreads();
    for (int i = t; i < NBUCK; i += 256)
        if (hist[i]) atomicAdd(&gcnt_pad[i * PAD], hist[i]);
}

__global__ __launch_bounds__(512) void p2_scan(const int* __restrict__ gcnt_pad,
                                               int* __restrict__ bucket_base,
                                               int* __restrict__ gcur_pad, int nE) {
    __shared__ int s[512];
    int t = threadIdx.x;
    int val = (t < NBUCK) ? gcnt_pad[t * PAD] : 0;
    s[t] = val;
    __syncthreads();
    for (int off = 1; off < 512; off <<= 1) {
        int x = (t >= off) ? s[t - off] : 0;
        __syncthreads();
        if (t >= off) s[t] += x;
        __syncthreads();
    }
    if (t < NBUCK) {
        int excl = s[t] - val;
        bucket_base[t] = excl;
        gcur_pad[t * PAD] = excl;
    }
    if (t == NBUCK - 1) bucket_base[NBUCK] = nE;
}

__global__ __launch_bounds__(256) void p3_scatter(const int* __restrict__ src,
                                                  const int* __restrict__ dst,
                                                  int* __restrict__ gcur_pad,
                                                  unsigned int* __restrict__ packed, int nE) {
    __shared__ int hist[NBUCK];
    __shared__ int cur[NBUCK];
    int t = threadIdx.x;
    int chunk = (nE + gridDim.x - 1) / gridDim.x;
    int lo = blockIdx.x * chunk;
    int hi = min(nE, lo + chunk);

    for (int i = t; i < NBUCK; i += 256) hist[i] = 0;
    __syncthreads();
    for (int e = lo + t; e < hi; e += 256)
        atomicAdd(&hist[dst[e] >> 8], 1);
    __syncthreads();
    for (int i = t; i < NBUCK; i += 256)
        cur[i] = hist[i] ? atomicAdd(&gcur_pad[i * PAD], hist[i]) : 0;
    __syncthreads();
    for (int e = lo + t; e < hi; e += 256) {
        int d = dst[e];
        int b = d >> 8;
        int pos = atomicAdd(&cur[b], 1);
        packed[pos] = ((unsigned int)(d & 255) << 17) | (unsigned int)src[e];
    }
}

__global__ __launch_bounds__(256) void p4_build(const unsigned int* __restrict__ packed,
                                                const int* __restrict__ bucket_base,
                                                int* __restrict__ rowptr,
                                                int* __restrict__ csr, int nN, int nE) {
    __shared__ int cnt[256];
    __shared__ int s[256];
    __shared__ int curs[256];
    int b = blockIdx.x;
    int t = threadIdx.x;
    int node0 = b << 8;
    int ebase = bucket_base[b];
    int eend  = bucket_base[b + 1];

    cnt[t] = 0;
    __syncthreads();
    for (int e = ebase + t; e < eend; e += 256)
        atomicAdd(&cnt[packed[e] >> 17], 1);
    __syncthreads();
    int val = cnt[t];
    s[t] = val;
    __syncthreads();
    for (int off = 1; off < 256; off <<= 1) {
        int x = (t >= off) ? s[t - off] : 0;
        __syncthreads();
        if (t >= off) s[t] += x;
        __syncthreads();
    }
    int excl = s[t] - val;
    int node = node0 + t;
    if (node < nN) rowptr[node] = ebase + excl;
    curs[t] = ebase + excl;
    if (b == gridDim.x - 1 && t == 0) rowptr[nN] = nE;
    __syncthreads();
    for (int e = ebase + t; e < eend; e += 256) {
        unsigned int p = packed[e];
        int d = p >> 17;
        int pos = atomicAdd(&curs[d], 1);
        csr[pos] = (int)(p & 0x1FFFFu);
    }
}

// ===== Dense projection GEMM (layers 1/2) =====
// outF = [relu]h @ Ws + b  (f32, self part -> d_out), outZ = [relu]h @ Wn (f32)
// Tile: 64 nodes x 128 cols per block (256 threads, 4x8 register tile).

template <bool RELU_IN>
__global__ __launch_bounds__(256) void k_gemm128(const float* __restrict__ h,
                                                 const float* __restrict__ Ws,
                                                 const float* __restrict__ Wn,
                                                 const float* __restrict__ bias,
                                                 float* __restrict__ outF,
                                                 float* __restrict__ outZ) {
    constexpr int WPAD = 132;
    __shared__ float sH[64][66];
    __shared__ float sW[64 * WPAD];
    __shared__ float sB[64];

    int t = threadIdx.x;
    for (int i = t; i < 64 * 128; i += 256) {
        int k = i >> 7, c = i & 127;
        sW[k * WPAD + c] = (c < 64) ? Ws[k * 64 + c] : Wn[k * 64 + (c - 64)];
    }
    if (t < 64) sB[t] = bias[t];

    int tr = t >> 4, tc = t & 15;
    int r0 = tr * 4, c0 = tc * 8;

    for (int tile = blockIdx.x; tile * 64 < N_NODES; tile += gridDim.x) {
        int node0 = tile * 64;
        __syncthreads();
        for (int i = t; i < 64 * 64; i += 256) {
            int n = i >> 6, k = i & 63;
            int node = node0 + n;
            float v = (node < N_NODES) ? h[(size_t)node * 64 + k] : 0.f;
            if (RELU_IN) v = fmaxf(v, 0.f);
            sH[n][k] = v;
        }
        __syncthreads();

        float acc[4][8];
#pragma unroll
        for (int j = 0; j < 4; ++j)
#pragma unroll
            for (int c = 0; c < 8; ++c) acc[j][c] = 0.f;

#pragma unroll 4
        for (int k = 0; k < 64; ++k) {
            float bb[8];
#pragma unroll
            for (int c = 0; c < 8; ++c) bb[c] = sW[k * WPAD + c0 + c];
#pragma unroll
            for (int j = 0; j < 4; ++j) {
                float a = sH[r0 + j][k];
#pragma unroll
                for (int c = 0; c < 8; ++c) acc[j][c] += a * bb[c];
            }
        }

#pragma unroll
        for (int j = 0; j < 4; ++j) {
            int node = node0 + r0 + j;
            if (node >= N_NODES) break;
            if (c0 < 64) {
                float4 o0, o1;
                o0.x = acc[j][0] + sB[c0 + 0]; o0.y = acc[j][1] + sB[c0 + 1];
                o0.z = acc[j][2] + sB[c0 + 2]; o0.w = acc[j][3] + sB[c0 + 3];
                o1.x = acc[j][4] + sB[c0 + 4]; o1.y = acc[j][5] + sB[c0 + 5];
                o1.z = acc[j][6] + sB[c0 + 6]; o1.w = acc[j][7] + sB[c0 + 7];
                float4* p = (float4*)(outF + (size_t)node * 64 + c0);
                p[0] = o0; p[1] = o1;
            } else {
                int zc = c0 - 64;
                float4 o0, o1;
                o0.x = acc[j][0]; o0.y = acc[j][1]; o0.z = acc[j][2]; o0.w = acc[j][3];
                o1.x = acc[j][4]; o1.y = acc[j][5]; o1.z = acc[j][6]; o1.w = acc[j][7];
                float4* p = (float4*)(outZ + (size_t)node * 64 + zc);
                p[0] = o0; p[1] = o1;
            }
        }
    }
}

// ===== Gather (layers 1/2): out[v] += segmean(z[src]) — r3-proven uniform-shfl =====
// Wave per node; lane = feature; 1 edge per step, 256B coalesced row loads.

__global__ __launch_bounds__(256, 8) void k_gather64u(const int* __restrict__ rowptr,
                                                      const int* __restrict__ csr,
                                                      const float* __restrict__ z,
                                                      float* __restrict__ out) {
    int t = threadIdx.x;
    int w = t >> 6, lane = t & 63;

    for (int v = blockIdx.x * 4 + w; v < N_NODES; v += gridDim.x * 4) {
        int beg = rowptr[v];
        int end = rowptr[v + 1];
        float acc = 0.f;

        for (int e0 = beg; e0 < end; e0 += 64) {
            int n = end - e0;
            if (n > 64) n = 64;
            int si = (lane < n) ? csr[e0 + lane] : 0;
            int i = 0;
            for (; i + 4 <= n; i += 4) {
                int s0 = __shfl(si, i);
                int s1 = __shfl(si, i + 1);
                int s2 = __shfl(si, i + 2);
                int s3 = __shfl(si, i + 3);
                float x0 = z[(size_t)s0 * 64 + lane];
                float x1 = z[(size_t)s1 * 64 + lane];
                float x2 = z[(size_t)s2 * 64 + lane];
                float x3 = z[(size_t)s3 * 64 + lane];
                acc += x0; acc += x1; acc += x2; acc += x3;
            }
            for (; i < n; ++i) {
                int sj = __shfl(si, i);
                acc += z[(size_t)sj * 64 + lane];
            }
        }

        float inv = 1.f / fmaxf((float)(end - beg), 1.f);
        out[(size_t)v * 64 + lane] += acc * inv;
    }
}

// ===== Layer 3 (verbatim r3-proven): project 16-wide, then gather small rows =====

__global__ __launch_bounds__(256) void k_pre3(const float* __restrict__ h,
                                              const float* __restrict__ Ws,
                                              const float* __restrict__ Wn,
                                              const float* __restrict__ bias,
                                              float* __restrict__ zbuf,
                                              float* __restrict__ wbuf) {
    __shared__ float sWs[64 * 16];
    __shared__ float sWn[64 * 16];
    __shared__ float sB[16];
    __shared__ float sH[4][64];

    int t = threadIdx.x;
    for (int i = t; i < 64 * 16; i += 256) {
        sWs[i] = Ws[i];
        sWn[i] = Wn[i];
    }
    if (t < 16) sB[t] = bias[t];
    __syncthreads();

    int w = t >> 6;
    int lane = t & 63;
    int j = lane & 15;
    int sel = lane >> 4;   // 0: wbuf (Ws+b), 1: zbuf (Wn), 2/3: idle in compute

    for (int v = blockIdx.x * 4 + w; v < N_NODES; v += gridDim.x * 4) {
        sH[w][lane] = fmaxf(h[(size_t)v * 64 + lane], 0.f);
        if (sel < 2) {
            const float* W = sel ? sWn : sWs;
            float o = sel ? 0.f : sB[j];
#pragma unroll 8
            for (int k = 0; k < 64; ++k) o += sH[w][k] * W[k * 16 + j];
            if (sel) zbuf[(size_t)v * 16 + j] = o;
            else     wbuf[(size_t)v * 16 + j] = o;
        }
    }
}

__global__ __launch_bounds__(256, 8) void k_gather3(const int* __restrict__ rowptr,
                                                    const int* __restrict__ csr,
                                                    const float* __restrict__ zbuf,
                                                    const float* __restrict__ wbuf,
                                                    float* __restrict__ out) {
    int t = threadIdx.x;
    int w = t >> 6;
    int lane = t & 63;
    int g = lane >> 4;     // edge subgroup 0..3
    int j = lane & 15;     // feature

    for (int v = blockIdx.x * 4 + w; v < N_NODES; v += gridDim.x * 4) {
        int beg = rowptr[v];
        int end = rowptr[v + 1];
        float acc = 0.f;
        int e = beg + g;
        for (; e + 4 < end; e += 8) {
            float a0 = zbuf[(size_t)csr[e] * 16 + j];
            float a1 = zbuf[(size_t)csr[e + 4] * 16 + j];
            acc += a0;
            acc += a1;
        }
        if (e < end) acc += zbuf[(size_t)csr[e] * 16 + j];
        acc += __shfl_xor(acc, 16);
        acc += __shfl_xor(acc, 32);
        if (g == 0) {
            float deg = (float)(end - beg);
            out[(size_t)v * 16 + j] = wbuf[(size_t)v * 16 + j] + acc / fmaxf(deg, 1.0f);
        }
    }
}

// ---------------- launch ----------------

extern "C" void kernel_launch(void* const* d_in, const int* in_sizes, int n_in,
                              void* d_out, int out_size, void* d_ws, size_t ws_size,
                              hipStream_t stream) {
    const float* feat = (const float*)d_in[0];
    const int* ei = (const int*)d_in[1];
    const int* src = ei;
    const int* dst = ei + N_EDGES;
    const float* Ws0 = (const float*)d_in[2];
    const float* Wn0 = (const float*)d_in[3];
    const float* b0  = (const float*)d_in[4];
    const float* Ws1 = (const float*)d_in[5];
    const float* Wn1 = (const float*)d_in[6];
    const float* b1  = (const float*)d_in[7];
    const float* Ws2 = (const float*)d_in[8];
    const float* Wn2 = (const float*)d_in[9];
    const float* b2  = (const float*)d_in[10];

    float* out = (float*)d_out;
    float* out_h3 = out;                                 // [N,16]
    float* out_e0 = out + (size_t)N_NODES * 16;          // [N,64]  pre-relu h1
    float* out_e1 = out + (size_t)N_NODES * (16 + 64);   // [N,64]  pre-relu h2

    char* ws = (char*)d_ws;
    size_t off = 0;
    auto alloc = [&](size_t bytes) -> void* {
        void* p = ws + off;
        off = (off + bytes + 255) & ~(size_t)255;
        return p;
    };
    int* gcnt_pad    = (int*)alloc(NBUCK * PAD * sizeof(int));
    int* gcur_pad    = (int*)alloc(NBUCK * PAD * sizeof(int));
    int* bucket_base = (int*)alloc((NBUCK + 1) * sizeof(int));
    int* rowptr      = (int*)alloc((N_NODES + 1) * sizeof(int));
    unsigned int* packed = (unsigned int*)alloc(N_EDGES * sizeof(int)); // 6.4 MB
    int* csr         = (int*)alloc(N_EDGES * sizeof(int));              // 6.4 MB
    float* zf        = (float*)alloc((size_t)N_NODES * 64 * sizeof(float)); // 25.6 MB
    // layer-3 z (fp32 [N,16] = 6.4 MB) aliases `packed` (dead after p4_build)
    float* zbuf3     = (float*)packed;
    (void)ws_size;

    hipMemsetAsync(gcnt_pad, 0, NBUCK * PAD * sizeof(int), stream);

    p1_hist<<<128, 256, 0, stream>>>(dst, gcnt_pad, N_EDGES);
    p2_scan<<<1, 512, 0, stream>>>(gcnt_pad, bucket_base, gcur_pad, N_EDGES);
    p3_scatter<<<128, 256, 0, stream>>>(src, dst, gcur_pad, packed, N_EDGES);
    p4_build<<<NBUCK, 256, 0, stream>>>(packed, bucket_base, rowptr, csr, N_NODES, N_EDGES);

    const int GT = (N_NODES + 63) / 64;   // 1563 gemm tiles

    // layer 1
    k_gemm128<false><<<GT, 256, 0, stream>>>(feat, Ws0, Wn0, b0, out_e0, zf);
    k_gather64u<<<2048, 256, 0, stream>>>(rowptr, csr, zf, out_e0);
    // layer 2
    k_gemm128<true><<<GT, 256, 0, stream>>>(out_e0, Ws1, Wn1, b1, out_e1, zf);
    k_gather64u<<<2048, 256, 0, stream>>>(rowptr, csr, zf, out_e1);
    // layer 3: r3-proven pipeline; self part written to out_h3, gather adds mean
    k_pre3<<<1024, 256, 0, stream>>>(out_e1, Ws2, Wn2, b2, zbuf3, out_h3);
    k_gather3<<<2048, 256, 0, stream>>>(rowptr, csr, zbuf3, out_h3, out_h3);
}

// Round 7
// 413.948 us; speedup vs baseline: 1.5305x; 1.1488x over previous
//
#include <hip/hip_runtime.h>
#include <hip/hip_bf16.h>

typedef __hip_bfloat16 bf16;

#define N_NODES 100000
#define N_EDGES 1600000
#define NBUCK 391           // ceil(N_NODES/256), bucket = dst >> 8
#define NBLK 128            // edge-chunk blocks for hist/scatter (must match q1/q4)

static __device__ __forceinline__ unsigned short f2bf(float x) {
    bf16 h = (bf16)x;
    return *reinterpret_cast<unsigned short*>(&h);
}

// ================= CSR build: deterministic bucket sort =================
// q1: per-block LDS histogram -> bh[b][i]
// q2: exclusive column scan over blocks (bh in place) + bucket totals
// q3: exclusive scan of totals -> bucket_base
// q4: scatter with cursors = bucket_base[i] + bh[b][i]  (no global atomics)
// p4: per-bucket local sort in LDS -> rowptr, csr

__global__ __launch_bounds__(256) void q1_hist(const int* __restrict__ dst,
                                               int* __restrict__ bh, int nE) {
    __shared__ int hist[NBUCK];
    int t = threadIdx.x, b = blockIdx.x;
    for (int i = t; i < NBUCK; i += 256) hist[i] = 0;
    __syncthreads();
    int chunk = (nE + NBLK - 1) / NBLK;
    int lo = b * chunk, hi = min(nE, lo + chunk);
    for (int e = lo + t; e < hi; e += 256) atomicAdd(&hist[dst[e] >> 8], 1);
    __syncthreads();
    for (int i = t; i < NBUCK; i += 256) bh[b * NBUCK + i] = hist[i];
}

__global__ __launch_bounds__(128) void q2_colscan(int* __restrict__ bh,
                                                  int* __restrict__ total) {
    __shared__ int s[128];
    int i = blockIdx.x;       // bucket
    int b = threadIdx.x;      // chunk-block
    int val = bh[b * NBUCK + i];
    s[b] = val;
    __syncthreads();
    for (int off = 1; off < 128; off <<= 1) {
        int x = (b >= off) ? s[b - off] : 0;
        __syncthreads();
        if (b >= off) s[b] += x;
        __syncthreads();
    }
    bh[b * NBUCK + i] = s[b] - val;        // exclusive over blocks
    if (b == 127) total[i] = s[127];
}

__global__ __launch_bounds__(512) void q3_scan(const int* __restrict__ total,
                                               int* __restrict__ bucket_base, int nE) {
    __shared__ int s[512];
    int t = threadIdx.x;
    int val = (t < NBUCK) ? total[t] : 0;
    s[t] = val;
    __syncthreads();
    for (int off = 1; off < 512; off <<= 1) {
        int x = (t >= off) ? s[t - off] : 0;
        __syncthreads();
        if (t >= off) s[t] += x;
        __syncthreads();
    }
    if (t < NBUCK) bucket_base[t] = s[t] - val;
    if (t == 0) bucket_base[NBUCK] = nE;
}

__global__ __launch_bounds__(256) void q4_scatter(const int* __restrict__ src,
                                                  const int* __restrict__ dst,
                                                  const int* __restrict__ bh,
                                                  const int* __restrict__ bucket_base,
                                                  unsigned int* __restrict__ packed, int nE) {
    __shared__ int cur[NBUCK];
    int t = threadIdx.x, b = blockIdx.x;
    for (int i = t; i < NBUCK; i += 256)
        cur[i] = bucket_base[i] + bh[b * NBUCK + i];
    __syncthreads();
    int chunk = (nE + NBLK - 1) / NBLK;
    int lo = b * chunk, hi = min(nE, lo + chunk);
    for (int e = lo + t; e < hi; e += 256) {
        int d = dst[e];
        int pos = atomicAdd(&cur[d >> 8], 1);
        packed[pos] = ((unsigned int)(d & 255) << 17) | (unsigned int)src[e];
    }
}

__global__ __launch_bounds__(256) void p4_build(const unsigned int* __restrict__ packed,
                                                const int* __restrict__ bucket_base,
                                                int* __restrict__ rowptr,
                                                int* __restrict__ csr, int nN, int nE) {
    __shared__ int cnt[256];
    __shared__ int s[256];
    __shared__ int curs[256];
    int b = blockIdx.x;
    int t = threadIdx.x;
    int node0 = b << 8;
    int ebase = bucket_base[b];
    int eend  = bucket_base[b + 1];

    cnt[t] = 0;
    __syncthreads();
    for (int e = ebase + t; e < eend; e += 256)
        atomicAdd(&cnt[packed[e] >> 17], 1);
    __syncthreads();
    int val = cnt[t];
    s[t] = val;
    __syncthreads();
    for (int off = 1; off < 256; off <<= 1) {
        int x = (t >= off) ? s[t - off] : 0;
        __syncthreads();
        if (t >= off) s[t] += x;
        __syncthreads();
    }
    int excl = s[t] - val;
    int node = node0 + t;
    if (node < nN) rowptr[node] = ebase + excl;
    curs[t] = ebase + excl;
    if (b == gridDim.x - 1 && t == 0) rowptr[nN] = nE;
    __syncthreads();
    for (int e = ebase + t; e < eend; e += 256) {
        unsigned int p = packed[e];
        int d = p >> 17;
        int pos = atomicAdd(&curs[d], 1);
        csr[pos] = (int)(p & 0x1FFFFu);
    }
}

// ===== Dense projection GEMM (layers 1/2) =====
// outF = [relu]h @ Ws + b (f32 -> d_out), outZ = [relu]h @ Wn (bf16-packed pairs)
// Tile: 64 nodes x 128 cols per block (256 threads, 4x8 register tile). Proven r6.

template <bool RELU_IN>
__global__ __launch_bounds__(256) void k_gemm128(const float* __restrict__ h,
                                                 const float* __restrict__ Ws,
                                                 const float* __restrict__ Wn,
                                                 const float* __restrict__ bias,
                                                 float* __restrict__ outF,
                                                 unsigned int* __restrict__ outZ) {
    constexpr int WPAD = 132;
    __shared__ float sH[64][66];
    __shared__ float sW[64 * WPAD];
    __shared__ float sB[64];

    int t = threadIdx.x;
    for (int i = t; i < 64 * 128; i += 256) {
        int k = i >> 7, c = i & 127;
        sW[k * WPAD + c] = (c < 64) ? Ws[k * 64 + c] : Wn[k * 64 + (c - 64)];
    }
    if (t < 64) sB[t] = bias[t];

    int tr = t >> 4, tc = t & 15;
    int r0 = tr * 4, c0 = tc * 8;

    for (int tile = blockIdx.x; tile * 64 < N_NODES; tile += gridDim.x) {
        int node0 = tile * 64;
        __syncthreads();
        for (int i = t; i < 64 * 64; i += 256) {
            int n = i >> 6, k = i & 63;
            int node = node0 + n;
            float v = (node < N_NODES) ? h[(size_t)node * 64 + k] : 0.f;
            if (RELU_IN) v = fmaxf(v, 0.f);
            sH[n][k] = v;
        }
        __syncthreads();

        float acc[4][8];
#pragma unroll
        for (int j = 0; j < 4; ++j)
#pragma unroll
            for (int c = 0; c < 8; ++c) acc[j][c] = 0.f;

#pragma unroll 4
        for (int k = 0; k < 64; ++k) {
            float bb[8];
#pragma unroll
            for (int c = 0; c < 8; ++c) bb[c] = sW[k * WPAD + c0 + c];
#pragma unroll
            for (int j = 0; j < 4; ++j) {
                float a = sH[r0 + j][k];
#pragma unroll
                for (int c = 0; c < 8; ++c) acc[j][c] += a * bb[c];
            }
        }

#pragma unroll
        for (int j = 0; j < 4; ++j) {
            int node = node0 + r0 + j;
            if (node >= N_NODES) break;
            if (c0 < 64) {
                float4 o0, o1;
                o0.x = acc[j][0] + sB[c0 + 0]; o0.y = acc[j][1] + sB[c0 + 1];
                o0.z = acc[j][2] + sB[c0 + 2]; o0.w = acc[j][3] + sB[c0 + 3];
                o1.x = acc[j][4] + sB[c0 + 4]; o1.y = acc[j][5] + sB[c0 + 5];
                o1.z = acc[j][6] + sB[c0 + 6]; o1.w = acc[j][7] + sB[c0 + 7];
                float4* p = (float4*)(outF + (size_t)node * 64 + c0);
                p[0] = o0; p[1] = o1;
            } else {
                int zc = c0 - 64;   // 0,8,16,...,56
                uint4 pk;
                pk.x = (unsigned)f2bf(acc[j][0]) | ((unsigned)f2bf(acc[j][1]) << 16);
                pk.y = (unsigned)f2bf(acc[j][2]) | ((unsigned)f2bf(acc[j][3]) << 16);
                pk.z = (unsigned)f2bf(acc[j][4]) | ((unsigned)f2bf(acc[j][5]) << 16);
                pk.w = (unsigned)f2bf(acc[j][6]) | ((unsigned)f2bf(acc[j][7]) << 16);
                *(uint4*)(outZ + (size_t)node * 32 + (zc >> 1)) = pk;
            }
        }
    }
}

// ===== Gather (layers 1/2, bf16 z): out[v] += segmean(z[src]) =====
// z rows = 32 dwords (64 bf16, 128B). Wave per node; sub=lane>>5 picks 1 of 2
// edges, f=lane&31 picks the dword -> 2 edges per wave-load.
// ALL __shfl are wave-uniform; only loads/adds are predicated.

__global__ __launch_bounds__(256, 8) void k_gather64b(const int* __restrict__ rowptr,
                                                      const int* __restrict__ csr,
                                                      const unsigned int* __restrict__ z,
                                                      float* __restrict__ out) {
    int t = threadIdx.x;
    int w = t >> 6, lane = t & 63;
    int sub = lane >> 5;
    int f = lane & 31;

    for (int v = blockIdx.x * 4 + w; v < N_NODES; v += gridDim.x * 4) {
        int beg = rowptr[v];
        int end = rowptr[v + 1];
        float ax = 0.f, ay = 0.f;

        for (int e0 = beg; e0 < end; e0 += 64) {
            int n = end - e0; if (n > 64) n = 64;
            int ids = (e0 + lane < end) ? csr[e0 + lane] : 0;
            int full = n >> 1;
            int i = 0;
            for (; i + 4 <= full; i += 4) {
                int r0 = __shfl(ids, 2 * i + sub);
                int r1 = __shfl(ids, 2 * i + 2 + sub);
                int r2 = __shfl(ids, 2 * i + 4 + sub);
                int r3 = __shfl(ids, 2 * i + 6 + sub);
                unsigned d0 = z[(size_t)r0 * 32 + f];
                unsigned d1 = z[(size_t)r1 * 32 + f];
                unsigned d2 = z[(size_t)r2 * 32 + f];
                unsigned d3 = z[(size_t)r3 * 32 + f];
                ax += __uint_as_float(d0 << 16); ay += __uint_as_float(d0 & 0xffff0000u);
                ax += __uint_as_float(d1 << 16); ay += __uint_as_float(d1 & 0xffff0000u);
                ax += __uint_as_float(d2 << 16); ay += __uint_as_float(d2 & 0xffff0000u);
                ax += __uint_as_float(d3 << 16); ay += __uint_as_float(d3 & 0xffff0000u);
            }
            for (; i < full; ++i) {
                int r = __shfl(ids, 2 * i + sub);
                unsigned d = z[(size_t)r * 32 + f];
                ax += __uint_as_float(d << 16); ay += __uint_as_float(d & 0xffff0000u);
            }
            // odd tail: edge n-1. shfl wave-uniform; load predicated.
            int rt = __shfl(ids, n - 1);
            if ((n & 1) && sub == 0) {
                unsigned d = z[(size_t)rt * 32 + f];
                ax += __uint_as_float(d << 16); ay += __uint_as_float(d & 0xffff0000u);
            }
        }

        ax += __shfl_xor(ax, 32);
        ay += __shfl_xor(ay, 32);
        if (sub == 0) {
            float inv = 1.f / fmaxf((float)(end - beg), 1.f);
            float2* op = (float2*)(out + (size_t)v * 64) + f;
            float2 cur = *op;
            cur.x += ax * inv;
            cur.y += ay * inv;
            *op = cur;
        }
    }
}

// ===== Layer 3 (verbatim r3/r6-proven): project 16-wide, then gather small rows =====

__global__ __launch_bounds__(256) void k_pre3(const float* __restrict__ h,
                                              const float* __restrict__ Ws,
                                              const float* __restrict__ Wn,
                                              const float* __restrict__ bias,
                                              float* __restrict__ zbuf,
                                              float* __restrict__ wbuf) {
    __shared__ float sWs[64 * 16];
    __shared__ float sWn[64 * 16];
    __shared__ float sB[16];
    __shared__ float sH[4][64];

    int t = threadIdx.x;
    for (int i = t; i < 64 * 16; i += 256) {
        sWs[i] = Ws[i];
        sWn[i] = Wn[i];
    }
    if (t < 16) sB[t] = bias[t];
    __syncthreads();

    int w = t >> 6;
    int lane = t & 63;
    int j = lane & 15;
    int sel = lane >> 4;

    for (int v = blockIdx.x * 4 + w; v < N_NODES; v += gridDim.x * 4) {
        sH[w][lane] = fmaxf(h[(size_t)v * 64 + lane], 0.f);
        if (sel < 2) {
            const float* W = sel ? sWn : sWs;
            float o = sel ? 0.f : sB[j];
#pragma unroll 8
            for (int k = 0; k < 64; ++k) o += sH[w][k] * W[k * 16 + j];
            if (sel) zbuf[(size_t)v * 16 + j] = o;
            else     wbuf[(size_t)v * 16 + j] = o;
        }
    }
}

__global__ __launch_bounds__(256, 8) void k_gather3(const int* __restrict__ rowptr,
                                                    const int* __restrict__ csr,
                                                    const float* __restrict__ zbuf,
                                                    const float* __restrict__ wbuf,
                                                    float* __restrict__ out) {
    int t = threadIdx.x;
    int w = t >> 6;
    int lane = t & 63;
    int g = lane >> 4;
    int j = lane & 15;

    for (int v = blockIdx.x * 4 + w; v < N_NODES; v += gridDim.x * 4) {
        int beg = rowptr[v];
        int end = rowptr[v + 1];
        float acc = 0.f;
        int e = beg + g;
        for (; e + 4 < end; e += 8) {
            float a0 = zbuf[(size_t)csr[e] * 16 + j];
            float a1 = zbuf[(size_t)csr[e + 4] * 16 + j];
            acc += a0;
            acc += a1;
        }
        if (e < end) acc += zbuf[(size_t)csr[e] * 16 + j];
        acc += __shfl_xor(acc, 16);
        acc += __shfl_xor(acc, 32);
        if (g == 0) {
            float deg = (float)(end - beg);
            out[(size_t)v * 16 + j] = wbuf[(size_t)v * 16 + j] + acc / fmaxf(deg, 1.0f);
        }
    }
}

// ---------------- launch ----------------

extern "C" void kernel_launch(void* const* d_in, const int* in_sizes, int n_in,
                              void* d_out, int out_size, void* d_ws, size_t ws_size,
                              hipStream_t stream) {
    const float* feat = (const float*)d_in[0];
    const int* ei = (const int*)d_in[1];
    const int* src = ei;
    const int* dst = ei + N_EDGES;
    const float* Ws0 = (const float*)d_in[2];
    const float* Wn0 = (const float*)d_in[3];
    const float* b0  = (const float*)d_in[4];
    const float* Ws1 = (const float*)d_in[5];
    const float* Wn1 = (const float*)d_in[6];
    const float* b1  = (const float*)d_in[7];
    const float* Ws2 = (const float*)d_in[8];
    const float* Wn2 = (const float*)d_in[9];
    const float* b2  = (const float*)d_in[10];

    float* out = (float*)d_out;
    float* out_h3 = out;                                 // [N,16]
    float* out_e0 = out + (size_t)N_NODES * 16;          // [N,64]  pre-relu h1
    float* out_e1 = out + (size_t)N_NODES * (16 + 64);   // [N,64]  pre-relu h2

    char* ws = (char*)d_ws;
    size_t off = 0;
    auto alloc = [&](size_t bytes) -> void* {
        void* p = ws + off;
        off = (off + bytes + 255) & ~(size_t)255;
        return p;
    };
    int* bh          = (int*)alloc((size_t)NBLK * NBUCK * sizeof(int));   // 200 KB
    int* total       = (int*)alloc(NBUCK * sizeof(int));
    int* bucket_base = (int*)alloc((NBUCK + 1) * sizeof(int));
    int* rowptr      = (int*)alloc((N_NODES + 1) * sizeof(int));
    unsigned int* packed = (unsigned int*)alloc(N_EDGES * sizeof(int));   // 6.4 MB
    int* csr         = (int*)alloc(N_EDGES * sizeof(int));                // 6.4 MB
    unsigned int* zb = (unsigned int*)alloc((size_t)N_NODES * 32 * sizeof(unsigned)); // 12.8 MB
    // layer-3 z (f32 [N,16] = 6.4 MB) aliases `packed` (dead after p4_build)
    float* zbuf3     = (float*)packed;
    (void)ws_size;

    q1_hist<<<NBLK, 256, 0, stream>>>(dst, bh, N_EDGES);
    q2_colscan<<<NBUCK, 128, 0, stream>>>(bh, total);
    q3_scan<<<1, 512, 0, stream>>>(total, bucket_base, N_EDGES);
    q4_scatter<<<NBLK, 256, 0, stream>>>(src, dst, bh, bucket_base, packed, N_EDGES);
    p4_build<<<NBUCK, 256, 0, stream>>>(packed, bucket_base, rowptr, csr, N_NODES, N_EDGES);

    const int GT = (N_NODES + 63) / 64;   // 1563 gemm tiles

    // layer 1
    k_gemm128<false><<<GT, 256, 0, stream>>>(feat, Ws0, Wn0, b0, out_e0, zb);
    k_gather64b<<<2048, 256, 0, stream>>>(rowptr, csr, zb, out_e0);
    // layer 2
    k_gemm128<true><<<GT, 256, 0, stream>>>(out_e0, Ws1, Wn1, b1, out_e1, zb);
    k_gather64b<<<2048, 256, 0, stream>>>(rowptr, csr, zb, out_e1);
    // layer 3: proven pipeline; self part -> out_h3, gather adds mean
    k_pre3<<<1024, 256, 0, stream>>>(out_e1, Ws2, Wn2, b2, zbuf3, out_h3);
    k_gather3<<<2048, 256, 0, stream>>>(rowptr, csr, zbuf3, out_h3, out_h3);
}